// Round 1
// baseline (321.459 us; speedup 1.0000x reference)
//
#include <hip/hip_runtime.h>
#include <stdint.h>

#define B_ 256
#define H_ 600
#define W_ 19
#define C1_ 40
#define C2_ 40
#define KH_ 29
#define PAD_ 14
#define NW_ 760       // C1_*W_
#define NWORDS_ 12    // ceil(760/64)
#define NJ_ 39
#define FIN_ 1560     // C2_*NJ_
#define FOUT_ 80
#define XSTR 604      // padded LDS column stride (mult of 4, bank-spread)

__device__ __forceinline__ float fsgn(float x){ return (x > 0.f) ? 1.f : ((x < 0.f) ? -1.f : 0.f); }
__device__ __forceinline__ int8_t isgn(float x){ return (int8_t)((x > 0.f) - (x < 0.f)); }

// bnp layout: [0:40) s1, [40:80) t1, [80:120) s2, [120:160) t2, [160:240) s3, [240:320) t3
__global__ void k0_setup(const float* __restrict__ w1, const float* __restrict__ w2,
                         const float* __restrict__ fc1w, const float* __restrict__ fc2w,
                         const float* __restrict__ g1, const float* __restrict__ b1,
                         const float* __restrict__ m1, const float* __restrict__ v1,
                         const float* __restrict__ g2, const float* __restrict__ b2,
                         const float* __restrict__ m2, const float* __restrict__ v2,
                         const float* __restrict__ g3, const float* __restrict__ b3,
                         const float* __restrict__ m3, const float* __restrict__ v3,
                         float* __restrict__ w1s, uint64_t* __restrict__ w2m,
                         int8_t* __restrict__ fc1s, int8_t* __restrict__ fc2s,
                         float* __restrict__ bnp)
{
  int tid = blockIdx.x * blockDim.x + threadIdx.x;
  int np  = gridDim.x * blockDim.x;
  for (int i = tid; i < C1_*KH_; i += np) w1s[i] = fsgn(w1[i]);
  for (int i = tid; i < C2_*NWORDS_; i += np){
    int c2 = i / NWORDS_, wd = i % NWORDS_;
    uint64_t pos = 0ull, neg = 0ull;
    for (int j = 0; j < 64; ++j){
      int idx = wd*64 + j;
      if (idx < NW_){
        float v = w2[c2*NW_ + idx];     // w2 flat = c2*760 + (c1*19 + w)
        if (v > 0.f)      pos |= (1ull << j);
        else if (v < 0.f) neg |= (1ull << j);
      }
    }
    w2m[c2*24 + wd]      = pos;
    w2m[c2*24 + 12 + wd] = neg;
  }
  for (int i = tid; i < FOUT_*FIN_; i += np) fc1s[i] = isgn(fc1w[i]);
  for (int i = tid; i < 2*FOUT_;    i += np) fc2s[i] = isgn(fc2w[i]);
  for (int i = tid; i < C1_; i += np){
    float s = __fdiv_rn(g1[i], __fsqrt_rn(__fadd_rn(v1[i], 1e-5f)));
    bnp[i] = s; bnp[40+i] = __fsub_rn(b1[i], __fmul_rn(m1[i], s));
  }
  for (int i = tid; i < C2_; i += np){
    float s = __fdiv_rn(g2[i], __fsqrt_rn(__fadd_rn(v2[i], 1e-5f)));
    bnp[80+i] = s; bnp[120+i] = __fsub_rn(b2[i], __fmul_rn(m2[i], s));
  }
  for (int i = tid; i < FOUT_; i += np){
    float s = __fdiv_rn(g3[i], __fsqrt_rn(__fadd_rn(v3[i], 1e-5f)));
    bnp[160+i] = s; bnp[240+i] = __fsub_rn(b3[i], __fmul_rn(m3[i], s));
  }
}

// conv1 (ascending-kh f32) + bn1 + prelu + sign -> ballot-packed bit planes.
// s1bits layout: [b][h][24] u64; words 0..11 = positive plane, 12..23 = negative plane,
// bit index i = c1*19 + w.
__global__ __launch_bounds__(768) void k1_conv1(const float* __restrict__ x,
                                                const float* __restrict__ w1s,
                                                const float* __restrict__ bnp,
                                                const float* __restrict__ a1p,
                                                uint64_t* __restrict__ s1bits)
{
  __shared__ float xs[W_ * XSTR];   // transposed: xs[w*XSTR + h]
  int b = blockIdx.x;
  const float* xb = x + (size_t)b * H_ * W_;
  for (int i = threadIdx.x; i < H_*W_; i += blockDim.x){
    int h = i / W_, w = i % W_;
    xs[w*XSTR + h] = xb[i];
  }
  __syncthreads();

  int i    = threadIdx.x;          // 0..767; 12 waves; lane = bit index within word
  int lane = i & 63, wave = i >> 6;
  bool valid = (i < NW_);
  int c1 = valid ? (i / W_) : 0;
  int w  = valid ? (i % W_) : 0;

  float wt[KH_];
  #pragma unroll
  for (int k = 0; k < KH_; ++k) wt[k] = w1s[c1*KH_ + k];
  float scale = bnp[c1], bias = bnp[40 + c1];
  float alpha = a1p[0];
  const float* xcol = &xs[w * XSTR];
  uint64_t* bbase = s1bits + (size_t)b * H_ * 24;

  auto emit = [&](int h, float u){
    float z = __fadd_rn(__fmul_rn(u, scale), bias);
    z = (z >= 0.f) ? z : __fmul_rn(alpha, z);
    if (!valid) z = 0.f;
    unsigned long long pos = __ballot(z > 0.f);
    unsigned long long neg = __ballot(z < 0.f);
    if (lane == 0){
      uint64_t* d = bbase + (size_t)h * 24;
      d[wave] = pos; d[wave + 12] = neg;
    }
  };

  // low edge: h in [0, 14)
  for (int h = 0; h < PAD_; ++h){
    float u = 0.f;
    for (int k = PAD_ - h; k < KH_; ++k)
      u = __fadd_rn(u, __fmul_rn(wt[k], xcol[h + k - PAD_]));
    emit(h, u);
  }
  // main: h in [14, 578), 47 chunks of 12
  for (int c = 0; c < 47; ++c){
    int h0 = PAD_ + 12*c;
    float xr[40];
    const float4* xp = (const float4*)&xcol[12*c];   // 16B-aligned (XSTR%4==0, 12c%4==0)
    #pragma unroll
    for (int q = 0; q < 10; ++q){
      float4 v = xp[q];
      xr[4*q+0] = v.x; xr[4*q+1] = v.y; xr[4*q+2] = v.z; xr[4*q+3] = v.w;
    }
    #pragma unroll
    for (int dh = 0; dh < 12; ++dh){
      float u = 0.f;
      #pragma unroll
      for (int k = 0; k < KH_; ++k)
        u = __builtin_fmaf(wt[k], xr[dh + k], u);    // product exact (+/-1) => fma == rn add
      emit(h0 + dh, u);
    }
  }
  // high edge: h in [578, 600)
  for (int h = 578; h < H_; ++h){
    int kmax = H_ - h + PAD_;
    float u = 0.f;
    for (int k = 0; k < KH_; ++k)
      if (k < kmax) u = __fadd_rn(u, __fmul_rn(wt[k], xcol[h + k - PAD_]));
    emit(h, u);
  }
}

// conv2 (popcount over bit planes, exact int) + bn2 + prelu + avgpool-sign -> sp int8
__global__ __launch_bounds__(256) void k2_conv2pool(const uint64_t* __restrict__ s1bits,
                                                    const uint64_t* __restrict__ w2m_g,
                                                    const float* __restrict__ bnp,   // s2 at [0], t2 at [40]
                                                    const float* __restrict__ a2p,
                                                    int8_t* __restrict__ sp)
{
  __shared__ uint64_t s1t[90][24];
  __shared__ uint64_t w2m[24][C2_];
  __shared__ float    z2[C2_][90];
  int t = blockIdx.x, b = blockIdx.y;
  int h0 = 75 * t;
  int rows = (H_ - h0 < 90) ? (H_ - h0) : 90;

  const uint64_t* src = s1bits + ((size_t)b * H_ + h0) * 24;
  for (int i = threadIdx.x; i < rows*24; i += 256) ((uint64_t*)s1t)[i] = src[i];
  for (int i = threadIdx.x; i < C2_*24; i += 256){
    int c2 = i / 24, wd = i % 24;
    w2m[wd][c2] = w2m_g[i];
  }
  __syncthreads();

  float alpha = a2p[0];
  for (int o = threadIdx.x; o < rows*C2_; o += 256){
    int hl = o / C2_, c2 = o % C2_;
    int y = 0;
    #pragma unroll
    for (int wd = 0; wd < NWORDS_; ++wd){
      uint64_t P  = s1t[hl][wd],      N  = s1t[hl][12 + wd];
      uint64_t WP = w2m[wd][c2],      WN = w2m[12 + wd][c2];
      y += __popcll(P & WP) - __popcll(P & WN) + __popcll(N & WN) - __popcll(N & WP);
    }
    float u = __fadd_rn(__fmul_rn((float)y, bnp[c2]), bnp[40 + c2]);
    z2[c2][hl] = (u >= 0.f) ? u : __fmul_rn(alpha, u);
  }
  __syncthreads();

  int nj = NJ_ - 5*t; if (nj > 5) nj = 5;
  for (int o = threadIdx.x; o < nj*C2_; o += 256){
    int jj = o / C2_, c2 = o % C2_;
    float s = 0.f;
    int base = 15 * jj;
    #pragma unroll
    for (int r = 0; r < 30; ++r) s = __fadd_rn(s, z2[c2][base + r]);  // sign(sum/30)==sign(sum)
    sp[(size_t)b * FIN_ + c2 * NJ_ + 5*t + jj] = (int8_t)((s > 0.f) - (s < 0.f));
  }
}

// fc1 (exact int) + bn3 + prelu + sign + fc2 (exact int) -> f32 integers
__global__ __launch_bounds__(128) void k3_fc(const int8_t* __restrict__ sp,
                                             const int8_t* __restrict__ fc1s,
                                             const int8_t* __restrict__ fc2s,
                                             const float* __restrict__ bnp,  // s3 at [0], t3 at [80]
                                             const float* __restrict__ a3p,
                                             float* __restrict__ out)
{
  __shared__ int8_t spl[FIN_];
  __shared__ int z3[FOUT_];
  int b = blockIdx.x;
  for (int i = threadIdx.x; i < FIN_; i += 128) spl[i] = sp[(size_t)b * FIN_ + i];
  __syncthreads();
  float alpha = a3p[0];
  if (threadIdx.x < FOUT_){
    int o = threadIdx.x;
    const int8_t* wr = fc1s + o * FIN_;
    int acc = 0;
    for (int i = 0; i < FIN_; ++i) acc += (int)spl[i] * (int)wr[i];
    float u = __fadd_rn(__fmul_rn((float)acc, bnp[o]), bnp[80 + o]);
    float z = (u >= 0.f) ? u : __fmul_rn(alpha, u);
    z3[o] = (z > 0.f) - (z < 0.f);
  }
  __syncthreads();
  if (threadIdx.x < 2){
    int k = threadIdx.x;
    int acc = 0;
    for (int o = 0; o < FOUT_; ++o) acc += z3[o] * (int)fc2s[k * FOUT_ + o];
    out[b*2 + k] = (float)acc;
  }
}

extern "C" void kernel_launch(void* const* d_in, const int* in_sizes, int n_in,
                              void* d_out, int out_size, void* d_ws, size_t ws_size,
                              hipStream_t stream)
{
  const float* x    = (const float*)d_in[0];
  const float* w1   = (const float*)d_in[1];
  const float* g1   = (const float*)d_in[2];
  const float* b1   = (const float*)d_in[3];
  const float* m1   = (const float*)d_in[4];
  const float* v1   = (const float*)d_in[5];
  const float* a1   = (const float*)d_in[6];
  const float* w2   = (const float*)d_in[7];
  const float* g2   = (const float*)d_in[8];
  const float* b2   = (const float*)d_in[9];
  const float* m2   = (const float*)d_in[10];
  const float* v2   = (const float*)d_in[11];
  const float* a2   = (const float*)d_in[12];
  const float* fc1w = (const float*)d_in[13];
  const float* g3   = (const float*)d_in[14];
  const float* b3   = (const float*)d_in[15];
  const float* m3   = (const float*)d_in[16];
  const float* v3   = (const float*)d_in[17];
  const float* a3   = (const float*)d_in[18];
  const float* fc2w = (const float*)d_in[19];

  char* ws = (char*)d_ws;
  uint64_t* s1bits = (uint64_t*)(ws);               // 256*600*24*8 = 29,491,200 B
  uint64_t* w2m    = (uint64_t*)(ws + 29491200);    // 7,680 B
  float*    w1s    = (float*)   (ws + 29498880);    // 4,640 B
  float*    bnp    = (float*)   (ws + 29503520);    // 1,280 B
  int8_t*   sp     = (int8_t*)  (ws + 29504800);    // 399,360 B
  int8_t*   fc1s   = (int8_t*)  (ws + 29904160);    // 124,800 B
  int8_t*   fc2s   = (int8_t*)  (ws + 30028960);    // 160 B

  k0_setup<<<dim3(128), dim3(256), 0, stream>>>(w1, w2, fc1w, fc2w,
                                                g1, b1, m1, v1,
                                                g2, b2, m2, v2,
                                                g3, b3, m3, v3,
                                                w1s, w2m, fc1s, fc2s, bnp);
  k1_conv1<<<dim3(B_), dim3(768), 0, stream>>>(x, w1s, bnp, a1, s1bits);
  k2_conv2pool<<<dim3(8, B_), dim3(256), 0, stream>>>(s1bits, w2m, bnp + 80, a2, sp);
  k3_fc<<<dim3(B_), dim3(128), 0, stream>>>(sp, fc1s, fc2s, bnp + 160, a3, (float*)d_out);
}

// Round 2
// 308.669 us; speedup vs baseline: 1.0414x; 1.0414x over previous
//
#include <hip/hip_runtime.h>
#include <stdint.h>

#define B_ 256
#define H_ 600
#define W_ 19
#define C1_ 40
#define C2_ 40
#define KH_ 29
#define PAD_ 14
#define NW_ 760       // C1_*W_
#define NWORDS_ 12    // ceil(760/64)
#define NJ_ 39
#define FIN_ 1560     // C2_*NJ_
#define FOUT_ 80
#define FCW_ 25       // ceil(1560/64)
#define XST2 328      // 300 rows + 28 halo, mult of 4 (16B-aligned float4 cols)
#define HS_ 300       // h rows per k1 block

__device__ __forceinline__ float fsgn(float x){ return (x > 0.f) ? 1.f : ((x < 0.f) ? -1.f : 0.f); }
__device__ __forceinline__ int8_t isgn(float x){ return (int8_t)((x > 0.f) - (x < 0.f)); }

// bnp layout: [0:40) s1, [40:80) t1, [80:120) s2, [120:160) t2, [160:240) s3, [240:320) t3
// bit index for s1 planes / w2m: idx = w*40 + c1   (w in [0,19), c1 in [0,40))
__global__ void k0_setup(const float* __restrict__ w1, const float* __restrict__ w2,
                         const float* __restrict__ fc1w, const float* __restrict__ fc2w,
                         const float* __restrict__ g1, const float* __restrict__ b1,
                         const float* __restrict__ m1, const float* __restrict__ v1,
                         const float* __restrict__ g2, const float* __restrict__ b2,
                         const float* __restrict__ m2, const float* __restrict__ v2,
                         const float* __restrict__ g3, const float* __restrict__ b3,
                         const float* __restrict__ m3, const float* __restrict__ v3,
                         float* __restrict__ w1s, uint64_t* __restrict__ w2m,
                         uint64_t* __restrict__ fc1p, int8_t* __restrict__ fc2s,
                         float* __restrict__ bnp)
{
  int tid = blockIdx.x * blockDim.x + threadIdx.x;
  int np  = gridDim.x * blockDim.x;
  for (int i = tid; i < C1_*KH_; i += np) w1s[i] = fsgn(w1[i]);
  // w2 bit-planes in the NEW bit order: bit idx = w*40 + c1
  for (int i = tid; i < C2_*NWORDS_; i += np){
    int c2 = i / NWORDS_, wd = i % NWORDS_;
    uint64_t pos = 0ull, neg = 0ull;
    for (int j = 0; j < 64; ++j){
      int idx = wd*64 + j;
      if (idx < NW_){
        int c1 = idx % 40, w = idx / 40;
        float v = w2[c2*NW_ + c1*W_ + w];    // w2 flat = c2*760 + c1*19 + w
        if (v > 0.f)      pos |= (1ull << j);
        else if (v < 0.f) neg |= (1ull << j);
      }
    }
    w2m[c2*24 + wd]      = pos;
    w2m[c2*24 + 12 + wd] = neg;
  }
  // fc1 bit-planes: fc1p[o*50 + wd] = pos, [o*50 + 25 + wd] = neg; bit j of wd = element wd*64+j
  for (int i = tid; i < FOUT_*2*FCW_; i += np){
    int o = i / (2*FCW_), r = i % (2*FCW_);
    int neg = r / FCW_, wd = r % FCW_;
    uint64_t m = 0ull;
    for (int j = 0; j < 64; ++j){
      int e = wd*64 + j;
      if (e < FIN_){
        float v = fc1w[o*FIN_ + e];
        bool bit = neg ? (v < 0.f) : (v > 0.f);
        if (bit) m |= (1ull << j);
      }
    }
    fc1p[o*(2*FCW_) + r] = m;
  }
  for (int i = tid; i < 2*FOUT_; i += np) fc2s[i] = isgn(fc2w[i]);
  for (int i = tid; i < C1_; i += np){
    float s = __fdiv_rn(g1[i], __fsqrt_rn(__fadd_rn(v1[i], 1e-5f)));
    bnp[i] = s; bnp[40+i] = __fsub_rn(b1[i], __fmul_rn(m1[i], s));
  }
  for (int i = tid; i < C2_; i += np){
    float s = __fdiv_rn(g2[i], __fsqrt_rn(__fadd_rn(v2[i], 1e-5f)));
    bnp[80+i] = s; bnp[120+i] = __fsub_rn(b2[i], __fmul_rn(m2[i], s));
  }
  for (int i = tid; i < FOUT_; i += np){
    float s = __fdiv_rn(g3[i], __fsqrt_rn(__fadd_rn(v3[i], 1e-5f)));
    bnp[160+i] = s; bnp[240+i] = __fsub_rn(b3[i], __fmul_rn(m3[i], s));
  }
}

// conv1 (ascending-kh f32, zero-padded halo => bit-exact edge order) + bn1 + sign
// (prelu dropped: alpha>0 is sign-invariant). Grid (B, 2); block handles 300 h rows.
// Bit order idx = w*40 + c1 => wave lanes span <=3 distinct w => LDS broadcast, no conflicts.
__global__ __launch_bounds__(768, 6) void k1_conv1(const float* __restrict__ x,
                                                   const float* __restrict__ w1s,
                                                   const float* __restrict__ bnp,
                                                   uint64_t* __restrict__ s1bits)
{
  __shared__ float xs[W_ * XST2];   // transposed: xs[w*XST2 + r], r = gh - h0 + 14
  int b = blockIdx.x, t = blockIdx.y;
  int h0 = HS_ * t;
  const float* xb = x + (size_t)b * H_ * W_;
  for (int i = threadIdx.x; i < XST2 * W_; i += 768){
    int r = i / W_, w = i % W_;
    int gh = h0 - PAD_ + r;
    xs[w*XST2 + r] = (gh >= 0 && gh < H_) ? xb[gh*W_ + w] : 0.f;
  }
  __syncthreads();

  int tid  = threadIdx.x;          // 0..767; 12 waves; lane = bit index within word
  int lane = tid & 63, wave = tid >> 6;
  bool valid = (tid < NW_);
  int c1 = tid % 40;
  int w  = valid ? (tid / 40) : 18;

  float wt[KH_];
  #pragma unroll
  for (int k = 0; k < KH_; ++k) wt[k] = w1s[c1*KH_ + k];
  float scale = bnp[c1], bias = bnp[40 + c1];
  const float* xcol = &xs[w * XST2];
  uint64_t* bbase = s1bits + ((size_t)b * H_ + h0) * 24;

  for (int c = 0; c < 25; ++c){                       // 25 chunks of 12 outputs
    float xr[40];
    const float4* xp = (const float4*)&xcol[12*c];    // 16B-aligned
    #pragma unroll
    for (int q = 0; q < 10; ++q){
      float4 v = xp[q];
      xr[4*q+0] = v.x; xr[4*q+1] = v.y; xr[4*q+2] = v.z; xr[4*q+3] = v.w;
    }
    #pragma unroll
    for (int dh = 0; dh < 12; ++dh){
      float u = 0.f;
      #pragma unroll
      for (int k = 0; k < KH_; ++k)
        u = __builtin_fmaf(wt[k], xr[dh + k], u);     // +/-1 product exact => fma == rn add
      float z = __fadd_rn(__fmul_rn(u, scale), bias); // sign(prelu(z)) == sign(z)
      unsigned long long pos = __ballot(valid && (z > 0.f));
      unsigned long long neg = __ballot(valid && (z < 0.f));
      if (lane == 0){
        uint64_t* d = bbase + (size_t)(12*c + dh) * 24;
        d[wave] = pos; d[wave + 12] = neg;
      }
    }
  }
}

// conv2 (popcount over bit planes, exact int) + bn2 + prelu + avgpool-sign -> sp int8
__global__ __launch_bounds__(256) void k2_conv2pool(const uint64_t* __restrict__ s1bits,
                                                    const uint64_t* __restrict__ w2m_g,
                                                    const float* __restrict__ bnp,   // s2 at [0], t2 at [40]
                                                    const float* __restrict__ a2p,
                                                    int8_t* __restrict__ sp)
{
  __shared__ uint64_t s1t[90][24];
  __shared__ uint64_t w2m[24][C2_];
  __shared__ float    z2[C2_][91];   // stride 91 (odd) => conflict-free column reads
  int t = blockIdx.x, b = blockIdx.y;
  int h0 = 75 * t;
  int rows = (H_ - h0 < 90) ? (H_ - h0) : 90;

  const uint64_t* src = s1bits + ((size_t)b * H_ + h0) * 24;
  for (int i = threadIdx.x; i < rows*24; i += 256) ((uint64_t*)s1t)[i] = src[i];
  for (int i = threadIdx.x; i < C2_*24; i += 256){
    int c2 = i / 24, wd = i % 24;
    w2m[wd][c2] = w2m_g[i];
  }
  __syncthreads();

  float alpha = a2p[0];
  for (int o = threadIdx.x; o < rows*C2_; o += 256){
    int hl = o / C2_, c2 = o % C2_;
    int y = 0;
    #pragma unroll
    for (int wd = 0; wd < NWORDS_; ++wd){
      uint64_t P  = s1t[hl][wd],      N  = s1t[hl][12 + wd];
      uint64_t WP = w2m[wd][c2],      WN = w2m[12 + wd][c2];
      y += __popcll(P & WP) - __popcll(P & WN) + __popcll(N & WN) - __popcll(N & WP);
    }
    float u = __fadd_rn(__fmul_rn((float)y, bnp[c2]), bnp[40 + c2]);
    z2[c2][hl] = (u >= 0.f) ? u : __fmul_rn(alpha, u);
  }
  __syncthreads();

  int nj = NJ_ - 5*t; if (nj > 5) nj = 5;
  for (int o = threadIdx.x; o < nj*C2_; o += 256){
    int jj = o / C2_, c2 = o % C2_;
    float s = 0.f;
    int base = 15 * jj;
    #pragma unroll
    for (int r = 0; r < 30; ++r) s = __fadd_rn(s, z2[c2][base + r]);  // sign(sum/30)==sign(sum)
    sp[(size_t)b * FIN_ + c2 * NJ_ + 5*t + jj] = (int8_t)((s > 0.f) - (s < 0.f));
  }
}

// fc1 (popcount, exact int) + bn3 + prelu + sign + fc2 (exact int) -> f32 integers
__global__ __launch_bounds__(128) void k3_fc(const int8_t* __restrict__ sp,
                                             const uint64_t* __restrict__ fc1p,
                                             const int8_t* __restrict__ fc2s,
                                             const float* __restrict__ bnp,  // s3 at [0], t3 at [80]
                                             const float* __restrict__ a3p,
                                             float* __restrict__ out)
{
  __shared__ uint64_t spP[FCW_], spN[FCW_];
  __shared__ int z3[FOUT_];
  int b = blockIdx.x;
  int lane = threadIdx.x & 63, wave = threadIdx.x >> 6;   // 2 waves
  const int8_t* spb = sp + (size_t)b * FIN_;
  for (int wd = wave; wd < FCW_; wd += 2){
    int e = wd*64 + lane;
    int v = (e < FIN_) ? (int)spb[e] : 0;
    unsigned long long p = __ballot(v > 0);
    unsigned long long n = __ballot(v < 0);
    if (lane == 0){ spP[wd] = p; spN[wd] = n; }
  }
  __syncthreads();
  float alpha = a3p[0];
  if (threadIdx.x < FOUT_){
    int o = threadIdx.x;
    const uint64_t* wp = fc1p + o * (2*FCW_);
    int acc = 0;
    #pragma unroll
    for (int wd = 0; wd < FCW_; ++wd){
      uint64_t P = spP[wd], N = spN[wd];
      uint64_t WP = wp[wd], WN = wp[FCW_ + wd];
      acc += __popcll(P & WP) + __popcll(N & WN) - __popcll(P & WN) - __popcll(N & WP);
    }
    float u = __fadd_rn(__fmul_rn((float)acc, bnp[o]), bnp[80 + o]);
    float z = (u >= 0.f) ? u : __fmul_rn(alpha, u);
    z3[o] = (z > 0.f) - (z < 0.f);
  }
  __syncthreads();
  if (threadIdx.x < 2){
    int k = threadIdx.x;
    int acc = 0;
    for (int o = 0; o < FOUT_; ++o) acc += z3[o] * (int)fc2s[k * FOUT_ + o];
    out[b*2 + k] = (float)acc;
  }
}

extern "C" void kernel_launch(void* const* d_in, const int* in_sizes, int n_in,
                              void* d_out, int out_size, void* d_ws, size_t ws_size,
                              hipStream_t stream)
{
  const float* x    = (const float*)d_in[0];
  const float* w1   = (const float*)d_in[1];
  const float* g1   = (const float*)d_in[2];
  const float* b1   = (const float*)d_in[3];
  const float* m1   = (const float*)d_in[4];
  const float* v1   = (const float*)d_in[5];
  const float* a1   = (const float*)d_in[6];   (void)a1;  // sign-invariant in k1
  const float* w2   = (const float*)d_in[7];
  const float* g2   = (const float*)d_in[8];
  const float* b2   = (const float*)d_in[9];
  const float* m2   = (const float*)d_in[10];
  const float* v2   = (const float*)d_in[11];
  const float* a2   = (const float*)d_in[12];
  const float* fc1w = (const float*)d_in[13];
  const float* g3   = (const float*)d_in[14];
  const float* b3   = (const float*)d_in[15];
  const float* m3   = (const float*)d_in[16];
  const float* v3   = (const float*)d_in[17];
  const float* a3   = (const float*)d_in[18];
  const float* fc2w = (const float*)d_in[19];

  char* ws = (char*)d_ws;
  uint64_t* s1bits = (uint64_t*)(ws);               // 256*600*24*8 = 29,491,200 B
  uint64_t* w2m    = (uint64_t*)(ws + 29491200);    // 7,680 B
  float*    w1s    = (float*)   (ws + 29498880);    // 4,640 B
  float*    bnp    = (float*)   (ws + 29503520);    // 1,280 B
  int8_t*   sp     = (int8_t*)  (ws + 29504800);    // 399,360 B
  uint64_t* fc1p   = (uint64_t*)(ws + 29904160);    // 80*50*8 = 32,000 B
  int8_t*   fc2s   = (int8_t*)  (ws + 29936160);    // 160 B

  k0_setup<<<dim3(128), dim3(256), 0, stream>>>(w1, w2, fc1w, fc2w,
                                                g1, b1, m1, v1,
                                                g2, b2, m2, v2,
                                                g3, b3, m3, v3,
                                                w1s, w2m, fc1p, fc2s, bnp);
  k1_conv1<<<dim3(B_, 2), dim3(768), 0, stream>>>(x, w1s, bnp, s1bits);
  k2_conv2pool<<<dim3(8, B_), dim3(256), 0, stream>>>(s1bits, w2m, bnp + 80, a2, sp);
  k3_fc<<<dim3(B_), dim3(128), 0, stream>>>(sp, fc1p, fc2s, bnp + 160, a3, (float*)d_out);
}

// Round 3
// 257.546 us; speedup vs baseline: 1.2482x; 1.1985x over previous
//
#include <hip/hip_runtime.h>
#include <stdint.h>

#define B_ 256
#define H_ 600
#define W_ 19
#define C1_ 40
#define C2_ 40
#define KH_ 29
#define PAD_ 14
#define NW_ 760       // C1_*W_
#define NWORDS_ 12    // ceil(760/64)
#define NJ_ 39
#define FIN_ 1560     // C2_*NJ_
#define FOUT_ 80
#define FCW_ 25       // ceil(1560/64)
#define XST2 328      // 300 rows + 28 halo, mult of 4 (16B-aligned float4 cols)
#define HS_ 300       // h rows per k1 block

__device__ __forceinline__ float fsgn(float x){ return (x > 0.f) ? 1.f : ((x < 0.f) ? -1.f : 0.f); }
__device__ __forceinline__ int8_t isgn(float x){ return (int8_t)((x > 0.f) - (x < 0.f)); }

// bnp layout: [0:40) s1, [40:80) t1, [80:120) s2, [120:160) t2, [160:240) s3, [240:320) t3
// bit index for s1 planes / w2m: idx = w*40 + c1   (w in [0,19), c1 in [0,40))
__global__ void k0_setup(const float* __restrict__ w1, const float* __restrict__ w2,
                         const float* __restrict__ fc1w, const float* __restrict__ fc2w,
                         const float* __restrict__ g1, const float* __restrict__ b1,
                         const float* __restrict__ m1, const float* __restrict__ v1,
                         const float* __restrict__ g2, const float* __restrict__ b2,
                         const float* __restrict__ m2, const float* __restrict__ v2,
                         const float* __restrict__ g3, const float* __restrict__ b3,
                         const float* __restrict__ m3, const float* __restrict__ v3,
                         float* __restrict__ w1s, uint64_t* __restrict__ w2m,
                         uint64_t* __restrict__ fc1p, int8_t* __restrict__ fc2s,
                         float* __restrict__ bnp)
{
  int tid = blockIdx.x * blockDim.x + threadIdx.x;
  int np  = gridDim.x * blockDim.x;
  int lane = threadIdx.x & 63;
  int gw   = tid >> 6;
  int nw   = np >> 6;

  for (int i = tid; i < C1_*KH_; i += np) w1s[i] = fsgn(w1[i]);

  // w2 bit planes via wave ballot: 960 words (c2, neg, wd); bit idx = w*40 + c1
  for (int v = gw; v < C2_*24; v += nw){
    int c2 = v / 24, r = v % 24;
    int neg = r / 12, wd = r % 12;
    int idx = wd*64 + lane;
    float val = 0.f;
    if (idx < NW_){
      int c1 = idx % 40, w = idx / 40;
      val = w2[c2*NW_ + c1*W_ + w];
    }
    unsigned long long m = __ballot(neg ? (val < 0.f) : (val > 0.f));
    if (lane == 0) w2m[c2*24 + r] = m;
  }
  // fc1 bit planes via wave ballot: 4000 words
  for (int v = gw; v < FOUT_*2*FCW_; v += nw){
    int o = v / (2*FCW_), r = v % (2*FCW_);
    int neg = r / FCW_, wd = r % FCW_;
    int e = wd*64 + lane;
    float val = (e < FIN_) ? fc1w[o*FIN_ + e] : 0.f;
    unsigned long long m = __ballot(neg ? (val < 0.f) : (val > 0.f));
    if (lane == 0) fc1p[o*(2*FCW_) + r] = m;
  }
  for (int i = tid; i < 2*FOUT_; i += np) fc2s[i] = isgn(fc2w[i]);
  for (int i = tid; i < C1_; i += np){
    float s = __fdiv_rn(g1[i], __fsqrt_rn(__fadd_rn(v1[i], 1e-5f)));
    bnp[i] = s; bnp[40+i] = __fsub_rn(b1[i], __fmul_rn(m1[i], s));
  }
  for (int i = tid; i < C2_; i += np){
    float s = __fdiv_rn(g2[i], __fsqrt_rn(__fadd_rn(v2[i], 1e-5f)));
    bnp[80+i] = s; bnp[120+i] = __fsub_rn(b2[i], __fmul_rn(m2[i], s));
  }
  for (int i = tid; i < FOUT_; i += np){
    float s = __fdiv_rn(g3[i], __fsqrt_rn(__fadd_rn(v3[i], 1e-5f)));
    bnp[160+i] = s; bnp[240+i] = __fsub_rn(b3[i], __fmul_rn(m3[i], s));
  }
}

// conv1 (ascending-kh f32, zero-padded halo => bit-exact edge order) + bn1 + sign.
// k-outer loop: weight from LDS (1 ds_read shared by 12 accumulators) keeps live set
// ~60 VGPR so the 348-FMA chunk schedules cleanly.
__global__ __launch_bounds__(768, 6) void k1_conv1(const float* __restrict__ x,
                                                   const float* __restrict__ w1s,
                                                   const float* __restrict__ bnp,
                                                   uint64_t* __restrict__ s1bits)
{
  __shared__ float xs[W_ * XST2];      // transposed: xs[w*XST2 + r], r = gh - h0 + 14
  __shared__ float wl[KH_ * 40];       // wl[k*40 + c1]
  int b = blockIdx.x, t = blockIdx.y;
  int h0 = HS_ * t;
  const float* xb = x + (size_t)b * H_ * W_;
  for (int i = threadIdx.x; i < XST2 * W_; i += 768){
    int r = i / W_, w = i % W_;
    int gh = h0 - PAD_ + r;
    xs[w*XST2 + r] = (gh >= 0 && gh < H_) ? xb[gh*W_ + w] : 0.f;
  }
  for (int i = threadIdx.x; i < KH_*40; i += 768){
    int k = i / 40, c1 = i % 40;
    wl[i] = w1s[c1*KH_ + k];
  }
  __syncthreads();

  int tid  = threadIdx.x;              // 0..767; 12 waves; lane = bit index within word
  int lane = tid & 63, wave = tid >> 6;
  bool valid = (tid < NW_);
  int c1 = tid % 40;
  int w  = valid ? (tid / 40) : 18;

  float scale = bnp[c1], bias = bnp[40 + c1];
  const float* xcol = &xs[w * XST2];
  const float* wcol = &wl[c1];
  uint64_t* bbase = s1bits + ((size_t)b * H_ + h0) * 24;

  for (int c = 0; c < 25; ++c){                       // 25 chunks of 12 outputs
    float xr[40];
    const float4* xp = (const float4*)&xcol[12*c];    // 16B-aligned
    #pragma unroll
    for (int q = 0; q < 10; ++q){
      float4 v = xp[q];
      xr[4*q+0] = v.x; xr[4*q+1] = v.y; xr[4*q+2] = v.z; xr[4*q+3] = v.w;
    }
    float acc[12];
    #pragma unroll
    for (int dh = 0; dh < 12; ++dh) acc[dh] = 0.f;
    #pragma unroll
    for (int k = 0; k < KH_; ++k){
      float wk = wcol[k*40];                          // LDS, 2-way bank max (free)
      #pragma unroll
      for (int dh = 0; dh < 12; ++dh)
        acc[dh] = __builtin_fmaf(wk, xr[dh + k], acc[dh]);  // ascending k: bit-exact
    }
    #pragma unroll
    for (int dh = 0; dh < 12; ++dh){
      float z = __fadd_rn(__fmul_rn(acc[dh], scale), bias); // sign(prelu(z))==sign(z)
      unsigned long long pos = __ballot(valid && (z > 0.f));
      unsigned long long neg = __ballot(valid && (z < 0.f));
      if (lane == 0){
        uint64_t* d = bbase + (size_t)(12*c + dh) * 24;
        d[wave] = pos; d[wave + 12] = neg;
      }
    }
  }
}

// conv2 + bn2 + prelu + avgpool-sign. Weights never zero => WN = ~WP, so
// y = nz(row) - 2*popc(M & (P ^ WP)), M = P|N. ~2.7x fewer VALU than 4-mask form.
__global__ __launch_bounds__(256) void k2_conv2pool(const uint64_t* __restrict__ s1bits,
                                                    const uint64_t* __restrict__ w2m_g,
                                                    const float* __restrict__ bnp,   // s2 at [0], t2 at [40]
                                                    const float* __restrict__ a2p,
                                                    int8_t* __restrict__ sp)
{
  __shared__ uint64_t s1P[90][12];
  __shared__ uint64_t s1M[90][12];
  __shared__ uint64_t w2p[12][C2_];
  __shared__ float    z2[C2_][91];   // stride 91 (odd) => conflict-free column reads
  __shared__ int      nzr[90];
  int t = blockIdx.x, b = blockIdx.y;
  int h0 = 75 * t;
  int rows = (H_ - h0 < 90) ? (H_ - h0) : 90;

  const uint64_t* src = s1bits + ((size_t)b * H_ + h0) * 24;
  for (int i = threadIdx.x; i < rows*12; i += 256){
    int r = i / 12, wd = i % 12;
    uint64_t P = src[r*24 + wd], N = src[r*24 + 12 + wd];
    s1P[r][wd] = P; s1M[r][wd] = P | N;
  }
  for (int i = threadIdx.x; i < 12*C2_; i += 256){
    int c2 = i / 12, wd = i % 12;
    w2p[wd][c2] = w2m_g[c2*24 + wd];    // pos plane only
  }
  __syncthreads();
  if (threadIdx.x < rows){
    int r = threadIdx.x, nz = 0;
    #pragma unroll
    for (int wd = 0; wd < NWORDS_; ++wd) nz += __popcll(s1M[r][wd]);
    nzr[r] = nz;
  }
  __syncthreads();

  float alpha = a2p[0];
  for (int o = threadIdx.x; o < rows*C2_; o += 256){
    int hl = o / C2_, c2 = o % C2_;
    int d = 0;
    #pragma unroll
    for (int wd = 0; wd < NWORDS_; ++wd)
      d += __popcll(s1M[hl][wd] & (s1P[hl][wd] ^ w2p[wd][c2]));
    int y = nzr[hl] - 2*d;
    float u = __fadd_rn(__fmul_rn((float)y, bnp[c2]), bnp[40 + c2]);
    z2[c2][hl] = (u >= 0.f) ? u : __fmul_rn(alpha, u);
  }
  __syncthreads();

  int nj = NJ_ - 5*t; if (nj > 5) nj = 5;
  for (int o = threadIdx.x; o < nj*C2_; o += 256){
    int jj = o / C2_, c2 = o % C2_;
    float s = 0.f;
    int base = 15 * jj;
    #pragma unroll
    for (int r = 0; r < 30; ++r) s = __fadd_rn(s, z2[c2][base + r]);  // sign(sum/30)==sign(sum)
    sp[(size_t)b * FIN_ + c2 * NJ_ + 5*t + jj] = (int8_t)((s > 0.f) - (s < 0.f));
  }
}

// fc1 (popcount, exact int) + bn3 + prelu + sign + fc2 (exact int) -> f32 integers
__global__ __launch_bounds__(128) void k3_fc(const int8_t* __restrict__ sp,
                                             const uint64_t* __restrict__ fc1p,
                                             const int8_t* __restrict__ fc2s,
                                             const float* __restrict__ bnp,  // s3 at [0], t3 at [80]
                                             const float* __restrict__ a3p,
                                             float* __restrict__ out)
{
  __shared__ uint64_t spP[FCW_], spN[FCW_];
  __shared__ int z3[FOUT_];
  int b = blockIdx.x;
  int lane = threadIdx.x & 63, wave = threadIdx.x >> 6;   // 2 waves
  const int8_t* spb = sp + (size_t)b * FIN_;
  for (int wd = wave; wd < FCW_; wd += 2){
    int e = wd*64 + lane;
    int v = (e < FIN_) ? (int)spb[e] : 0;
    unsigned long long p = __ballot(v > 0);
    unsigned long long n = __ballot(v < 0);
    if (lane == 0){ spP[wd] = p; spN[wd] = n; }
  }
  __syncthreads();
  float alpha = a3p[0];
  if (threadIdx.x < FOUT_){
    int o = threadIdx.x;
    const uint64_t* wp = fc1p + o * (2*FCW_);
    int acc = 0;
    #pragma unroll
    for (int wd = 0; wd < FCW_; ++wd){
      uint64_t P = spP[wd], N = spN[wd];
      uint64_t WP = wp[wd], WN = wp[FCW_ + wd];
      acc += __popcll(P & WP) + __popcll(N & WN) - __popcll(P & WN) - __popcll(N & WP);
    }
    float u = __fadd_rn(__fmul_rn((float)acc, bnp[o]), bnp[80 + o]);
    float z = (u >= 0.f) ? u : __fmul_rn(alpha, u);
    z3[o] = (z > 0.f) - (z < 0.f);
  }
  __syncthreads();
  if (threadIdx.x < 2){
    int k = threadIdx.x;
    int acc = 0;
    for (int o = 0; o < FOUT_; ++o) acc += z3[o] * (int)fc2s[k * FOUT_ + o];
    out[b*2 + k] = (float)acc;
  }
}

extern "C" void kernel_launch(void* const* d_in, const int* in_sizes, int n_in,
                              void* d_out, int out_size, void* d_ws, size_t ws_size,
                              hipStream_t stream)
{
  const float* x    = (const float*)d_in[0];
  const float* w1   = (const float*)d_in[1];
  const float* g1   = (const float*)d_in[2];
  const float* b1   = (const float*)d_in[3];
  const float* m1   = (const float*)d_in[4];
  const float* v1   = (const float*)d_in[5];
  const float* a1   = (const float*)d_in[6];   (void)a1;  // sign-invariant in k1
  const float* w2   = (const float*)d_in[7];
  const float* g2   = (const float*)d_in[8];
  const float* b2   = (const float*)d_in[9];
  const float* m2   = (const float*)d_in[10];
  const float* v2   = (const float*)d_in[11];
  const float* a2   = (const float*)d_in[12];
  const float* fc1w = (const float*)d_in[13];
  const float* g3   = (const float*)d_in[14];
  const float* b3   = (const float*)d_in[15];
  const float* m3   = (const float*)d_in[16];
  const float* v3   = (const float*)d_in[17];
  const float* a3   = (const float*)d_in[18];
  const float* fc2w = (const float*)d_in[19];

  char* ws = (char*)d_ws;
  uint64_t* s1bits = (uint64_t*)(ws);               // 256*600*24*8 = 29,491,200 B
  uint64_t* w2m    = (uint64_t*)(ws + 29491200);    // 7,680 B
  float*    w1s    = (float*)   (ws + 29498880);    // 4,640 B
  float*    bnp    = (float*)   (ws + 29503520);    // 1,280 B
  int8_t*   sp     = (int8_t*)  (ws + 29504800);    // 399,360 B
  uint64_t* fc1p   = (uint64_t*)(ws + 29904160);    // 80*50*8 = 32,000 B
  int8_t*   fc2s   = (int8_t*)  (ws + 29936160);    // 160 B

  k0_setup<<<dim3(128), dim3(256), 0, stream>>>(w1, w2, fc1w, fc2w,
                                                g1, b1, m1, v1,
                                                g2, b2, m2, v2,
                                                g3, b3, m3, v3,
                                                w1s, w2m, fc1p, fc2s, bnp);
  k1_conv1<<<dim3(B_, 2), dim3(768), 0, stream>>>(x, w1s, bnp, s1bits);
  k2_conv2pool<<<dim3(8, B_), dim3(256), 0, stream>>>(s1bits, w2m, bnp + 80, a2, sp);
  k3_fc<<<dim3(B_), dim3(128), 0, stream>>>(sp, fc1p, fc2s, bnp + 160, a3, (float*)d_out);
}

// Round 4
// 244.451 us; speedup vs baseline: 1.3150x; 1.0536x over previous
//
#include <hip/hip_runtime.h>
#include <stdint.h>

#define B_ 256
#define H_ 600
#define W_ 19
#define C1_ 40
#define C2_ 40
#define KH_ 29
#define PAD_ 14
#define NW_ 760       // C1_*W_
#define NWORDS_ 12    // ceil(760/64)
#define NJ_ 39
#define FIN_ 1560     // C2_*NJ_
#define FOUT_ 80
#define FCW_ 25       // ceil(1560/64)
#define XST2 328      // 300 rows + 28 halo, mult of 4 (16B-aligned float4 cols)
#define HS_ 300       // h rows per k1 block

typedef float v2f __attribute__((ext_vector_type(2)));

__device__ __forceinline__ float fsgn(float x){ return (x > 0.f) ? 1.f : ((x < 0.f) ? -1.f : 0.f); }
__device__ __forceinline__ int8_t isgn(float x){ return (int8_t)((x > 0.f) - (x < 0.f)); }

// bnp layout: [0:40) s1, [40:80) t1, [80:120) s2, [120:160) t2, [160:240) s3, [240:320) t3
// s1bits layout: [b][h][wd][2] u64, wd 0..11: (P, M) pair; bit idx = w*40 + c1
__global__ void k0_setup(const float* __restrict__ w1, const float* __restrict__ w2,
                         const float* __restrict__ fc1w, const float* __restrict__ fc2w,
                         const float* __restrict__ g1, const float* __restrict__ b1,
                         const float* __restrict__ m1, const float* __restrict__ v1,
                         const float* __restrict__ g2, const float* __restrict__ b2,
                         const float* __restrict__ m2, const float* __restrict__ v2,
                         const float* __restrict__ g3, const float* __restrict__ b3,
                         const float* __restrict__ m3, const float* __restrict__ v3,
                         float* __restrict__ w1s, uint64_t* __restrict__ w2m,
                         uint64_t* __restrict__ fc1p, int8_t* __restrict__ fc2s,
                         float* __restrict__ bnp)
{
  int tid = blockIdx.x * blockDim.x + threadIdx.x;
  int np  = gridDim.x * blockDim.x;
  int lane = threadIdx.x & 63;
  int gw   = tid >> 6;
  int nw   = np >> 6;

  for (int i = tid; i < C1_*KH_; i += np) w1s[i] = fsgn(w1[i]);

  // w2 pos plane only (weights never 0 => neg = ~pos within M); bit idx = w*40+c1
  for (int v = gw; v < C2_*NWORDS_; v += nw){
    int c2 = v / NWORDS_, wd = v % NWORDS_;
    int idx = wd*64 + lane;
    float val = 0.f;
    if (idx < NW_){
      int c1 = idx % 40, w = idx / 40;
      val = w2[c2*NW_ + c1*W_ + w];
    }
    unsigned long long m = __ballot(val > 0.f);
    if (lane == 0) w2m[c2*NWORDS_ + wd] = m;
  }
  // fc1 bit planes: fc1p[o*50 + wd]=pos, [o*50+25+wd]=neg
  for (int v = gw; v < FOUT_*2*FCW_; v += nw){
    int o = v / (2*FCW_), r = v % (2*FCW_);
    int neg = r / FCW_, wd = r % FCW_;
    int e = wd*64 + lane;
    float val = (e < FIN_) ? fc1w[o*FIN_ + e] : 0.f;
    unsigned long long m = __ballot(neg ? (val < 0.f) : (val > 0.f));
    if (lane == 0) fc1p[o*(2*FCW_) + r] = m;
  }
  for (int i = tid; i < 2*FOUT_; i += np) fc2s[i] = isgn(fc2w[i]);
  for (int i = tid; i < C1_; i += np){
    float s = __fdiv_rn(g1[i], __fsqrt_rn(__fadd_rn(v1[i], 1e-5f)));
    bnp[i] = s; bnp[40+i] = __fsub_rn(b1[i], __fmul_rn(m1[i], s));
  }
  for (int i = tid; i < C2_; i += np){
    float s = __fdiv_rn(g2[i], __fsqrt_rn(__fadd_rn(v2[i], 1e-5f)));
    bnp[80+i] = s; bnp[120+i] = __fsub_rn(b2[i], __fmul_rn(m2[i], s));
  }
  for (int i = tid; i < FOUT_; i += np){
    float s = __fdiv_rn(g3[i], __fsqrt_rn(__fadd_rn(v3[i], 1e-5f)));
    bnp[160+i] = s; bnp[240+i] = __fsub_rn(b3[i], __fmul_rn(m3[i], s));
  }
}

// conv1 (ascending-k f32, zero halo) + bn1 + sign -> (P, M) word pairs.
// Fully hand-unrolled k-loop; float2-paired outputs -> v_pk_fma_f32.
#define FMA2(a,b,c) __builtin_elementwise_fma(a,b,c)
#define KE(k) { v2f wk = wt2[k]; \
  a0 = FMA2(wk, E[(k)/2+0], a0); a1 = FMA2(wk, E[(k)/2+1], a1); \
  a2 = FMA2(wk, E[(k)/2+2], a2); a3 = FMA2(wk, E[(k)/2+3], a3); \
  a4 = FMA2(wk, E[(k)/2+4], a4); a5 = FMA2(wk, E[(k)/2+5], a5); }
#define KO(k) { v2f wk = wt2[k]; \
  a0 = FMA2(wk, O[((k)-1)/2+0], a0); a1 = FMA2(wk, O[((k)-1)/2+1], a1); \
  a2 = FMA2(wk, O[((k)-1)/2+2], a2); a3 = FMA2(wk, O[((k)-1)/2+3], a3); \
  a4 = FMA2(wk, O[((k)-1)/2+4], a4); a5 = FMA2(wk, O[((k)-1)/2+5], a5); }

__global__ __launch_bounds__(768, 3) void k1_conv1(const float* __restrict__ x,
                                                   const float* __restrict__ w1s,
                                                   const float* __restrict__ bnp,
                                                   uint64_t* __restrict__ s1bits)
{
  __shared__ float xs[W_ * XST2];      // transposed: xs[w*XST2 + r], r = gh - h0 + 14
  int b = blockIdx.x, t = blockIdx.y;
  int h0 = HS_ * t;
  const float* xb = x + (size_t)b * H_ * W_;
  for (int i = threadIdx.x; i < XST2 * W_; i += 768){
    int r = i / W_, w = i % W_;
    int gh = h0 - PAD_ + r;
    xs[w*XST2 + r] = (gh >= 0 && gh < H_) ? xb[gh*W_ + w] : 0.f;
  }
  __syncthreads();

  int tid  = threadIdx.x;              // 12 waves; lane = bit index within word
  int lane = tid & 63, wave = tid >> 6;
  bool valid = (tid < NW_);
  int c1 = tid % 40;
  int w  = valid ? (tid / 40) : 18;

  v2f wt2[KH_];                        // duplicated weight pairs, resident
  #pragma unroll
  for (int k = 0; k < KH_; ++k){ float wv = w1s[c1*KH_ + k]; wt2[k] = (v2f){wv, wv}; }
  float scale = bnp[c1], bias = bnp[40 + c1];
  if (!valid){ scale = __builtin_nanf(""); bias = scale; }  // NaN => both ballots false
  const float* xcol = &xs[w * XST2];
  uint64_t* bbase = s1bits + ((size_t)b * H_ + h0) * 24;

  for (int c = 0; c < 25; ++c){                       // 25 chunks of 12 outputs
    v2f E[20];
    const float4* xp = (const float4*)&xcol[12*c];    // 16B-aligned
    #pragma unroll
    for (int q = 0; q < 10; ++q){
      float4 v = xp[q];
      E[2*q]   = (v2f){v.x, v.y};
      E[2*q+1] = (v2f){v.z, v.w};
    }
    v2f O[19];
    #pragma unroll
    for (int m = 0; m < 19; ++m) O[m] = (v2f){E[m].y, E[m+1].x};

    v2f a0 = (v2f)0.f, a1 = (v2f)0.f, a2 = (v2f)0.f,
        a3 = (v2f)0.f, a4 = (v2f)0.f, a5 = (v2f)0.f;
    KE(0)  KO(1)  KE(2)  KO(3)  KE(4)  KO(5)  KE(6)  KO(7)  KE(8)  KO(9)
    KE(10) KO(11) KE(12) KO(13) KE(14) KO(15) KE(16) KO(17) KE(18) KO(19)
    KE(20) KO(21) KE(22) KO(23) KE(24) KO(25) KE(26) KO(27) KE(28)

    v2f accs[6] = {a0, a1, a2, a3, a4, a5};
    #pragma unroll
    for (int j = 0; j < 6; ++j){
      float zx = __fadd_rn(__fmul_rn(accs[j].x, scale), bias);  // sign(prelu)==sign
      float zy = __fadd_rn(__fmul_rn(accs[j].y, scale), bias);
      unsigned long long px = __ballot(zx > 0.f);
      unsigned long long nx = __ballot(zx < 0.f);
      unsigned long long py = __ballot(zy > 0.f);
      unsigned long long ny = __ballot(zy < 0.f);
      if (lane == 0){
        int h = 12*c + 2*j;
        ulonglong2 v0; v0.x = px; v0.y = px | nx;
        ulonglong2 v1; v1.x = py; v1.y = py | ny;
        *(ulonglong2*)(bbase + (size_t)h     * 24 + wave*2) = v0;
        *(ulonglong2*)(bbase + (size_t)(h+1) * 24 + wave*2) = v1;
      }
    }
  }
}

// conv2 + bn2 + prelu + avgpool-sign. thread = (c2, window jl); weights register-resident;
// row (P,M) read as single b128, 2-way broadcast across wave. One barrier pair, no z2 roundtrip.
__global__ __launch_bounds__(320) void k2_conv2pool(const uint64_t* __restrict__ s1bits,
                                                    const uint64_t* __restrict__ w2m_g,
                                                    const float* __restrict__ bnp,   // s2 at [0], t2 at [40]
                                                    const float* __restrict__ a2p,
                                                    int8_t* __restrict__ sp)
{
  __shared__ uint64_t st[135][NWORDS_][2];   // (P, M) — 25,920 B
  __shared__ int nz[136];
  int t = blockIdx.x, b = blockIdx.y;
  int j0 = 8*t;
  int nwin = NJ_ - j0; if (nwin > 8) nwin = 8;
  int r0 = 15*j0;
  int rows = H_ - r0; if (rows > 135) rows = 135;
  int tid = threadIdx.x;

  const ulonglong2* src = (const ulonglong2*)(s1bits + ((size_t)b * H_ + r0) * 24);
  ulonglong2* dst = (ulonglong2*)st;
  for (int i = tid; i < rows*NWORDS_; i += 320) dst[i] = src[i];
  __syncthreads();
  for (int r = tid; r < rows; r += 320){
    int s = 0;
    #pragma unroll
    for (int wd = 0; wd < NWORDS_; ++wd) s += __popcll(st[r][wd][1]);
    nz[r] = s;
  }
  __syncthreads();

  int c2 = tid % 40, jl = tid / 40;
  if (jl < nwin){
    uint64_t WP[NWORDS_];
    #pragma unroll
    for (int wd = 0; wd < NWORDS_; ++wd) WP[wd] = w2m_g[c2*NWORDS_ + wd];
    float s2 = bnp[c2], t2 = bnp[40 + c2], alpha = a2p[0];
    float psum = 0.f;
    int rbase = 15*jl;
    for (int rr = 0; rr < 30; ++rr){
      int r = rbase + rr;
      int d = 0;
      #pragma unroll
      for (int wd = 0; wd < NWORDS_; ++wd){
        ulonglong2 pm = *(const ulonglong2*)&st[r][wd][0];   // (P, M) one b128
        d += __popcll(pm.y & (pm.x ^ WP[wd]));
      }
      int y = nz[r] - 2*d;
      float u = __fadd_rn(__fmul_rn((float)y, s2), t2);
      float z = (u >= 0.f) ? u : __fmul_rn(alpha, u);
      psum = __fadd_rn(psum, z);                              // ascending r, bit-exact
    }
    sp[(size_t)b * FIN_ + c2 * NJ_ + (j0 + jl)] = (int8_t)((psum > 0.f) - (psum < 0.f));
  }
}

// fc1 (popcount, exact int) + bn3 + prelu + sign + fc2 (exact int) -> f32 integers
__global__ __launch_bounds__(128) void k3_fc(const int8_t* __restrict__ sp,
                                             const uint64_t* __restrict__ fc1p,
                                             const int8_t* __restrict__ fc2s,
                                             const float* __restrict__ bnp,  // s3 at [0], t3 at [80]
                                             const float* __restrict__ a3p,
                                             float* __restrict__ out)
{
  __shared__ uint64_t spP[FCW_], spN[FCW_];
  __shared__ int z3[FOUT_];
  int b = blockIdx.x;
  int lane = threadIdx.x & 63, wave = threadIdx.x >> 6;   // 2 waves
  const int8_t* spb = sp + (size_t)b * FIN_;
  for (int wd = wave; wd < FCW_; wd += 2){
    int e = wd*64 + lane;
    int v = (e < FIN_) ? (int)spb[e] : 0;
    unsigned long long p = __ballot(v > 0);
    unsigned long long n = __ballot(v < 0);
    if (lane == 0){ spP[wd] = p; spN[wd] = n; }
  }
  __syncthreads();
  float alpha = a3p[0];
  if (threadIdx.x < FOUT_){
    int o = threadIdx.x;
    const uint64_t* wp = fc1p + o * (2*FCW_);
    int acc = 0;
    #pragma unroll
    for (int wd = 0; wd < FCW_; ++wd){
      uint64_t P = spP[wd], N = spN[wd];
      uint64_t WP = wp[wd], WN = wp[FCW_ + wd];
      acc += __popcll(P & WP) + __popcll(N & WN) - __popcll(P & WN) - __popcll(N & WP);
    }
    float u = __fadd_rn(__fmul_rn((float)acc, bnp[o]), bnp[80 + o]);
    float z = (u >= 0.f) ? u : __fmul_rn(alpha, u);
    z3[o] = (z > 0.f) - (z < 0.f);
  }
  __syncthreads();
  if (threadIdx.x < 2){
    int k = threadIdx.x;
    int acc = 0;
    for (int o = 0; o < FOUT_; ++o) acc += z3[o] * (int)fc2s[k * FOUT_ + o];
    out[b*2 + k] = (float)acc;
  }
}

extern "C" void kernel_launch(void* const* d_in, const int* in_sizes, int n_in,
                              void* d_out, int out_size, void* d_ws, size_t ws_size,
                              hipStream_t stream)
{
  const float* x    = (const float*)d_in[0];
  const float* w1   = (const float*)d_in[1];
  const float* g1   = (const float*)d_in[2];
  const float* b1   = (const float*)d_in[3];
  const float* m1   = (const float*)d_in[4];
  const float* v1   = (const float*)d_in[5];
  const float* a1   = (const float*)d_in[6];   (void)a1;  // sign-invariant in k1
  const float* w2   = (const float*)d_in[7];
  const float* g2   = (const float*)d_in[8];
  const float* b2   = (const float*)d_in[9];
  const float* m2   = (const float*)d_in[10];
  const float* v2   = (const float*)d_in[11];
  const float* a2   = (const float*)d_in[12];
  const float* fc1w = (const float*)d_in[13];
  const float* g3   = (const float*)d_in[14];
  const float* b3   = (const float*)d_in[15];
  const float* m3   = (const float*)d_in[16];
  const float* v3   = (const float*)d_in[17];
  const float* a3   = (const float*)d_in[18];
  const float* fc2w = (const float*)d_in[19];

  char* ws = (char*)d_ws;
  uint64_t* s1bits = (uint64_t*)(ws);               // 256*600*24*8 = 29,491,200 B
  uint64_t* w2m    = (uint64_t*)(ws + 29491200);    // 40*12*8 = 3,840 B
  float*    w1s    = (float*)   (ws + 29495040);    // 4,640 B
  float*    bnp    = (float*)   (ws + 29499680);    // 1,280 B
  int8_t*   sp     = (int8_t*)  (ws + 29500960);    // 399,360 B
  uint64_t* fc1p   = (uint64_t*)(ws + 29900320);    // 80*50*8 = 32,000 B
  int8_t*   fc2s   = (int8_t*)  (ws + 29932320);    // 160 B

  k0_setup<<<dim3(128), dim3(256), 0, stream>>>(w1, w2, fc1w, fc2w,
                                                g1, b1, m1, v1,
                                                g2, b2, m2, v2,
                                                g3, b3, m3, v3,
                                                w1s, w2m, fc1p, fc2s, bnp);
  k1_conv1<<<dim3(B_, 2), dim3(768), 0, stream>>>(x, w1s, bnp, s1bits);
  k2_conv2pool<<<dim3(5, B_), dim3(320), 0, stream>>>(s1bits, w2m, bnp + 80, a2, sp);
  k3_fc<<<dim3(B_), dim3(128), 0, stream>>>(sp, fc1p, fc2s, bnp + 160, a3, (float*)d_out);
}

// Round 6
// 219.922 us; speedup vs baseline: 1.4617x; 1.1115x over previous
//
#include <hip/hip_runtime.h>
#include <stdint.h>

#define B_ 256
#define H_ 600
#define W_ 19
#define C1_ 40
#define C2_ 40
#define KH_ 29
#define PAD_ 14
#define NW_ 760       // C1_*W_
#define NWORDS_ 12    // ceil(760/64)
#define NJ_ 39
#define FIN_ 1560     // C2_*NJ_
#define FOUT_ 80
#define FCW_ 25       // ceil(1560/64)
#define XST2 329      // 300 rows + 28 halo + 1 (odd => bank-spread staging)
#define HS_ 300       // h rows per k1 block

__device__ __forceinline__ float fsgn(float x){ return (x > 0.f) ? 1.f : ((x < 0.f) ? -1.f : 0.f); }
__device__ __forceinline__ int8_t isgn(float x){ return (int8_t)((x > 0.f) - (x < 0.f)); }

// bnp layout: [0:40) s1, [40:80) t1, [80:120) s2, [120:160) t2, [160:240) s3, [240:320) t3
// s1bits layout: [b][wd][h] ulonglong2 {P, M}; bit idx within word-plane = w*40 + c1
__global__ void k0_setup(const float* __restrict__ w1, const float* __restrict__ w2,
                         const float* __restrict__ fc1w, const float* __restrict__ fc2w,
                         const float* __restrict__ g1, const float* __restrict__ b1,
                         const float* __restrict__ m1, const float* __restrict__ v1,
                         const float* __restrict__ g2, const float* __restrict__ b2,
                         const float* __restrict__ m2, const float* __restrict__ v2,
                         const float* __restrict__ g3, const float* __restrict__ b3,
                         const float* __restrict__ m3, const float* __restrict__ v3,
                         float* __restrict__ w1s, uint64_t* __restrict__ w2m,
                         uint64_t* __restrict__ fc1p, int8_t* __restrict__ fc2s,
                         float* __restrict__ bnp)
{
  int tid = blockIdx.x * blockDim.x + threadIdx.x;
  int np  = gridDim.x * blockDim.x;
  int lane = threadIdx.x & 63;
  int gw   = tid >> 6;
  int nw   = np >> 6;

  for (int i = tid; i < C1_*KH_; i += np) w1s[i] = fsgn(w1[i]);

  // w2 pos plane only (weights never 0 => neg = ~pos within M); bit idx = w*40+c1
  for (int v = gw; v < C2_*NWORDS_; v += nw){
    int c2 = v / NWORDS_, wd = v % NWORDS_;
    int idx = wd*64 + lane;
    float val = 0.f;
    if (idx < NW_){
      int c1 = idx % 40, w = idx / 40;
      val = w2[c2*NW_ + c1*W_ + w];
    }
    unsigned long long m = __ballot(val > 0.f);
    if (lane == 0) w2m[c2*NWORDS_ + wd] = m;
  }
  // fc1 bit planes: fc1p[o*50 + wd]=pos, [o*50+25+wd]=neg
  for (int v = gw; v < FOUT_*2*FCW_; v += nw){
    int o = v / (2*FCW_), r = v % (2*FCW_);
    int neg = r / FCW_, wd = r % FCW_;
    int e = wd*64 + lane;
    float val = (e < FIN_) ? fc1w[o*FIN_ + e] : 0.f;
    unsigned long long m = __ballot(neg ? (val < 0.f) : (val > 0.f));
    if (lane == 0) fc1p[o*(2*FCW_) + r] = m;
  }
  for (int i = tid; i < 2*FOUT_; i += np) fc2s[i] = isgn(fc2w[i]);
  for (int i = tid; i < C1_; i += np){
    float s = __fdiv_rn(g1[i], __fsqrt_rn(__fadd_rn(v1[i], 1e-5f)));
    bnp[i] = s; bnp[40+i] = __fsub_rn(b1[i], __fmul_rn(m1[i], s));
  }
  for (int i = tid; i < C2_; i += np){
    float s = __fdiv_rn(g2[i], __fsqrt_rn(__fadd_rn(v2[i], 1e-5f)));
    bnp[80+i] = s; bnp[120+i] = __fsub_rn(b2[i], __fmul_rn(m2[i], s));
  }
  for (int i = tid; i < FOUT_; i += np){
    float s = __fdiv_rn(g3[i], __fsqrt_rn(__fadd_rn(v3[i], 1e-5f)));
    bnp[160+i] = s; bnp[240+i] = __fsub_rn(b3[i], __fmul_rn(m3[i], s));
  }
}

// ---- k1: conv1 via register-rotation sliding window ----
// Output local row rn uses xs[rn .. rn+28]; slot s holds xs[m], m === s (mod 29).
template<int T>
__device__ __forceinline__ float acc29(float (&xw)[29], float (&wt)[29]){
  float a = 0.f;
  #pragma unroll
  for (int k = 0; k < 29; ++k)
    a = __builtin_fmaf(wt[k], xw[(T + k) % 29], a);   // ascending k: bit-exact chain
  return a;
}

template<int T>
__device__ __forceinline__ void step1(float (&xw)[29], float (&wt)[29],
                                      const float* xck, ulonglong2* ob,
                                      float scale, float bias, int lane){
  xw[(T + 28) % 29] = xck[T + 28];                    // 1 broadcast ds_read_b32
  float acc = acc29<T>(xw, wt);
  float z = __fadd_rn(__fmul_rn(acc, scale), bias);   // sign(prelu(z)) == sign(z)
  unsigned long long pp = __ballot(z > 0.f);          // NaN (invalid lanes) -> false
  unsigned long long nn = __ballot(z < 0.f);
  if (lane == 0){ ulonglong2 v; v.x = pp; v.y = pp | nn; ob[T] = v; }
}

#define S1(t) step1<t>(xw, wt, xck, ob, scale, bias, lane);

__global__ __launch_bounds__(768, 6) void k1_conv1(const float* __restrict__ x,
                                                   const float* __restrict__ w1s,
                                                   const float* __restrict__ bnp,
                                                   uint64_t* __restrict__ s1bits)
{
  __shared__ float xs[W_ * XST2];      // transposed: xs[w*XST2 + r], xs[r]=x[h0-14+r]
  int b = blockIdx.x, t = blockIdx.y;
  int h0 = HS_ * t;
  const float* xb = x + (size_t)b * H_ * W_;
  for (int i = threadIdx.x; i < (HS_ + 28) * W_; i += 768){
    int r = i / W_, w = i % W_;
    int gh = h0 - PAD_ + r;
    xs[w*XST2 + r] = (gh >= 0 && gh < H_) ? xb[gh*W_ + w] : 0.f;
  }
  __syncthreads();

  int tid  = threadIdx.x;              // 12 waves; lane = bit index within word
  int lane = tid & 63, wave = tid >> 6;
  bool valid = (tid < NW_);
  int c1 = tid % 40;
  int w  = valid ? (tid / 40) : 18;

  float wt[KH_];
  #pragma unroll
  for (int k = 0; k < KH_; ++k) wt[k] = w1s[c1*KH_ + k];
  float scale = bnp[c1], bias = bnp[40 + c1];
  if (!valid){ scale = __builtin_nanf(""); bias = scale; }  // NaN => both ballots false
  const float* xcol = &xs[w * XST2];

  float xw[29];
  #pragma unroll
  for (int s = 0; s < 28; ++s) xw[s] = xcol[s];       // slots 0..27 = xs[0..27]

  ulonglong2* obase = (ulonglong2*)s1bits + ((size_t)(b*12 + wave) * H_ + h0);

  #pragma unroll 1
  for (int c = 0; c < 10; ++c){                       // 10 chunks x 29 outputs = 290
    const float* xck = xcol + 29*c;
    ulonglong2* ob = obase + 29*c;
    S1(0)  S1(1)  S1(2)  S1(3)  S1(4)  S1(5)  S1(6)  S1(7)  S1(8)  S1(9)
    S1(10) S1(11) S1(12) S1(13) S1(14) S1(15) S1(16) S1(17) S1(18) S1(19)
    S1(20) S1(21) S1(22) S1(23) S1(24) S1(25) S1(26) S1(27) S1(28)
  }
  {                                                   // tail: outputs 290..299
    const float* xck = xcol + 290;
    ulonglong2* ob = obase + 290;
    S1(0) S1(1) S1(2) S1(3) S1(4) S1(5) S1(6) S1(7) S1(8) S1(9)
  }
}

// ---- k2: conv2 + bn2 + prelu + avgpool-sign; row data register-resident ----
// One block per batch; lane = row; weights/bn via uniform scalar loads.
__global__ __launch_bounds__(640) void k2_conv2pool(const uint64_t* __restrict__ s1bits,
                                                    const uint64_t* __restrict__ w2m_g,
                                                    const float* __restrict__ bnp,   // s2 at [0], t2 at [40]
                                                    const float* __restrict__ a2p,
                                                    int8_t* __restrict__ sp)
{
  __shared__ float z[C2_][640];        // 102,400 B
  int b = blockIdx.x;
  int tid = threadIdx.x;
  int rowc = (tid < H_) ? tid : (H_ - 1);

  uint64_t Pv[NWORDS_], Mv[NWORDS_];
  const ulonglong2* sb = (const ulonglong2*)s1bits + (size_t)b * NWORDS_ * H_;
  #pragma unroll
  for (int wd = 0; wd < NWORDS_; ++wd){
    ulonglong2 pm = sb[(size_t)wd * H_ + rowc];       // coalesced: lane=row
    Pv[wd] = pm.x; Mv[wd] = pm.y;
  }
  int nzv = 0;
  #pragma unroll
  for (int wd = 0; wd < NWORDS_; ++wd) nzv += __popcll(Mv[wd]);

  float alpha = a2p[0];
  #pragma unroll 2
  for (int c2 = 0; c2 < C2_; ++c2){
    int dsum = 0;
    #pragma unroll
    for (int wd = 0; wd < NWORDS_; ++wd)
      dsum += __popcll(Mv[wd] & (Pv[wd] ^ w2m_g[c2*NWORDS_ + wd]));  // WP uniform -> s_load
    int y = nzv - 2*dsum;
    float u = __fadd_rn(__fmul_rn((float)y, bnp[c2]), bnp[40 + c2]); // uniform -> s_load
    z[c2][tid] = (u >= 0.f) ? u : __fmul_rn(alpha, u);
  }
  __syncthreads();

  for (int o = tid; o < C2_*NJ_; o += 640){
    int c2 = o / NJ_, j = o % NJ_;
    float s = 0.f;
    int base = 15*j;
    #pragma unroll
    for (int r = 0; r < 30; ++r) s = __fadd_rn(s, z[c2][base + r]);  // ascending, bit-exact
    sp[(size_t)b*FIN_ + o] = (int8_t)((s > 0.f) - (s < 0.f));        // o = c2*39+j layout
  }
}

// fc1 (popcount, exact int) + bn3 + prelu + sign + fc2 (exact int) -> f32 integers
__global__ __launch_bounds__(128) void k3_fc(const int8_t* __restrict__ sp,
                                             const uint64_t* __restrict__ fc1p,
                                             const int8_t* __restrict__ fc2s,
                                             const float* __restrict__ bnp,  // s3 at [0], t3 at [80]
                                             const float* __restrict__ a3p,
                                             float* __restrict__ out)
{
  __shared__ uint64_t spP[FCW_], spN[FCW_];
  __shared__ int z3[FOUT_];
  int b = blockIdx.x;
  int lane = threadIdx.x & 63, wave = threadIdx.x >> 6;   // 2 waves
  const int8_t* spb = sp + (size_t)b * FIN_;
  for (int wd = wave; wd < FCW_; wd += 2){
    int e = wd*64 + lane;
    int v = (e < FIN_) ? (int)spb[e] : 0;
    unsigned long long p = __ballot(v > 0);
    unsigned long long n = __ballot(v < 0);
    if (lane == 0){ spP[wd] = p; spN[wd] = n; }
  }
  __syncthreads();
  float alpha = a3p[0];
  if (threadIdx.x < FOUT_){
    int o = threadIdx.x;
    const uint64_t* wp = fc1p + o * (2*FCW_);
    int acc = 0;
    #pragma unroll
    for (int wd = 0; wd < FCW_; ++wd){
      uint64_t P = spP[wd], N = spN[wd];
      uint64_t WP = wp[wd], WN = wp[FCW_ + wd];
      acc += __popcll(P & WP) + __popcll(N & WN) - __popcll(P & WN) - __popcll(N & WP);
    }
    float u = __fadd_rn(__fmul_rn((float)acc, bnp[o]), bnp[80 + o]);
    float z = (u >= 0.f) ? u : __fmul_rn(alpha, u);
    z3[o] = (z > 0.f) - (z < 0.f);
  }
  __syncthreads();
  if (threadIdx.x < 2){
    int k = threadIdx.x;
    int acc = 0;
    for (int o = 0; o < FOUT_; ++o) acc += z3[o] * (int)fc2s[k * FOUT_ + o];
    out[b*2 + k] = (float)acc;
  }
}

extern "C" void kernel_launch(void* const* d_in, const int* in_sizes, int n_in,
                              void* d_out, int out_size, void* d_ws, size_t ws_size,
                              hipStream_t stream)
{
  const float* x    = (const float*)d_in[0];
  const float* w1   = (const float*)d_in[1];
  const float* g1   = (const float*)d_in[2];
  const float* b1   = (const float*)d_in[3];
  const float* m1   = (const float*)d_in[4];
  const float* v1   = (const float*)d_in[5];
  const float* a1   = (const float*)d_in[6];   (void)a1;  // sign-invariant in k1
  const float* w2   = (const float*)d_in[7];
  const float* g2   = (const float*)d_in[8];
  const float* b2   = (const float*)d_in[9];
  const float* m2   = (const float*)d_in[10];
  const float* v2   = (const float*)d_in[11];
  const float* a2   = (const float*)d_in[12];
  const float* fc1w = (const float*)d_in[13];
  const float* g3   = (const float*)d_in[14];
  const float* b3   = (const float*)d_in[15];
  const float* m3   = (const float*)d_in[16];
  const float* v3   = (const float*)d_in[17];
  const float* a3   = (const float*)d_in[18];
  const float* fc2w = (const float*)d_in[19];

  char* ws = (char*)d_ws;
  uint64_t* s1bits = (uint64_t*)(ws);               // 256*12*600*16 = 29,491,200 B
  uint64_t* w2m    = (uint64_t*)(ws + 29491200);    // 40*12*8 = 3,840 B
  float*    w1s    = (float*)   (ws + 29495040);    // 4,640 B
  float*    bnp    = (float*)   (ws + 29499680);    // 1,280 B
  int8_t*   sp     = (int8_t*)  (ws + 29500960);    // 399,360 B
  uint64_t* fc1p   = (uint64_t*)(ws + 29900320);    // 80*50*8 = 32,000 B
  int8_t*   fc2s   = (int8_t*)  (ws + 29932320);    // 160 B

  k0_setup<<<dim3(128), dim3(256), 0, stream>>>(w1, w2, fc1w, fc2w,
                                                g1, b1, m1, v1,
                                                g2, b2, m2, v2,
                                                g3, b3, m3, v3,
                                                w1s, w2m, fc1p, fc2s, bnp);
  k1_conv1<<<dim3(B_, 2), dim3(768), 0, stream>>>(x, w1s, bnp, s1bits);
  k2_conv2pool<<<dim3(B_), dim3(640), 0, stream>>>(s1bits, w2m, bnp + 80, a2, sp);
  k3_fc<<<dim3(B_), dim3(128), 0, stream>>>(sp, fc1p, fc2s, bnp + 160, a3, (float*)d_out);
}